// Round 7
// baseline (159.865 us; speedup 1.0000x reference)
//
#include <hip/hip_runtime.h>
#include <hip/hip_bf16.h>

typedef __bf16 bf16;
typedef __bf16 bf16x8 __attribute__((ext_vector_type(8)));
typedef __bf16 bf16x4 __attribute__((ext_vector_type(4)));
typedef float  f32x4  __attribute__((ext_vector_type(4)));

#define MFMA16(A, B, C) __builtin_amdgcn_mfma_f32_16x16x32_bf16((A), (B), (C), 0, 0, 0)
#define WAITV(N) asm volatile("s_waitcnt vmcnt(" #N ")" ::: "memory")
#define BARRIER() asm volatile("s_barrier" ::: "memory")

static constexpr int Bn = 4;
static constexpr int T  = 4096;
static constexpr int Cd = 1024;
static constexpr int H  = 64;
static constexpr int NG = 192;
static constexpr int CH = 8;            // K-tiles (64 keys each) per split-K chunk
static constexpr int SLOTS_PER_B = 288; // sum_{qt=0..63} ceil((qt+1)/8)
static constexpr float QSCALE = 0.03125f; // 1/sqrt(C) = 1/32, folded into q

// async global->LDS DMA, 16B per lane; LDS dest = wave-uniform base + lane*16
__device__ inline void dma16(const void* g, void* l) {
    __builtin_amdgcn_global_load_lds(
        (const __attribute__((address_space(1))) unsigned int*)g,
        (__attribute__((address_space(3))) unsigned int*)l, 16, 0, 0);
}

__device__ inline bf16x8 cvt_bf16x8(float4 a, float4 b) {
    bf16x8 r;
    r[0] = (bf16)a.x; r[1] = (bf16)a.y; r[2] = (bf16)a.z; r[3] = (bf16)a.w;
    r[4] = (bf16)b.x; r[5] = (bf16)b.y; r[6] = (bf16)b.z; r[7] = (bf16)b.w;
    return r;
}

// ---------------------------------------------------------------------------
// Kernel 1: coalesced transpose W=[Wq|Wk|Wv] ([C][H] fp32) -> Wt[192][1024] bf16
// ---------------------------------------------------------------------------
__global__ __launch_bounds__(256) void wt_kernel(const float* __restrict__ Wq,
                                                 const float* __restrict__ Wk,
                                                 const float* __restrict__ Wv,
                                                 bf16* __restrict__ Wt) {
    __shared__ float s[64][65];
    const int cb = blockIdx.x;
    const int m  = blockIdx.y;
    const float* W = (m == 0) ? Wq : (m == 1) ? Wk : Wv;
    for (int i = threadIdx.x; i < 64 * 64; i += 256) {
        const int c = i >> 6, h = i & 63;
        s[c][h] = W[(cb * 64 + c) * H + h];
    }
    __syncthreads();
    for (int i = threadIdx.x; i < 64 * 64; i += 256) {
        const int n = i >> 6, c = i & 63;
        Wt[(m * 64 + n) * Cd + cb * 64 + c] = (bf16)s[c][n];
    }
}

// ---------------------------------------------------------------------------
// Kernel 2: QKV projection v7. 256 blocks (1/CU), 512 thr = 8 waves (2x4).
// Block = 64 rows x 192 cols. Triple-buffered DMA staging of x AND Wt with
// raw s_barrier + s_waitcnt vmcnt(5) pipeline (prefetch depth 2; loads stay
// in flight across barriers). XOR 16B-chunk swizzle; no padding (DMA reqt).
// ---------------------------------------------------------------------------
__global__ __launch_bounds__(512, 2) void proj_kernel(const float* __restrict__ x,
                                                      const bf16* __restrict__ Wt,
                                                      bf16* __restrict__ qw,
                                                      bf16* __restrict__ kw,
                                                      bf16* __restrict__ vtw) {
    const int tid  = threadIdx.x;
    const int lane = tid & 63;
    const int w    = tid >> 6;       // 0..7
    const int wr   = w >> 2;         // row-group 0..1 (32 rows each)
    const int wc   = w & 3;          // col-group 0..3 (48 cols each)
    const int ml   = lane & 15;
    const int quad = lane >> 4;

    const long r0 = (long)blockIdx.x * 64;

    __shared__ float sX[3][64][64];   // 16 KB/buf, chunk c stores global c^(row&15)
    __shared__ bf16  sW[3][192][64];  // 24 KB/buf, chunk c stores global c^(row&7)

    // x DMA: wave w stages rows [w*8, w*8+8) in two instrs (4 rows each)
    const int xr0 = w * 8 + (lane >> 4);
    const int xch = lane & 15;
    const float* gx0 = x + (r0 + xr0) * Cd + ((xch ^ (xr0 & 15)) << 2);
    const float* gx1 = x + (r0 + xr0 + 4) * Cd + ((xch ^ ((xr0 + 4) & 15)) << 2);
    // Wt DMA: wave w stages rows [w*24, w*24+24) in three instrs (8 rows each)
    const int wr8 = lane >> 3;        // swizzle key: (w*24+off+wr8)&7 == wr8
    const int wsw = ((lane & 7) ^ wr8) << 3;
    const bf16* gw0 = Wt + (long)(w * 24 + 0  + wr8) * Cd + wsw;
    const bf16* gw1 = Wt + (long)(w * 24 + 8  + wr8) * Cd + wsw;
    const bf16* gw2 = Wt + (long)(w * 24 + 16 + wr8) * Cd + wsw;

    f32x4 acc[2][3];
    #pragma unroll
    for (int g = 0; g < 2; ++g)
        #pragma unroll
        for (int f = 0; f < 3; ++f) acc[g][f] = f32x4{0.f, 0.f, 0.f, 0.f};

    // prologue: stage tiles 0 (buf0) and 1 (buf1); 5 DMAs each per wave
    dma16(gx0, &sX[0][w * 8][0]);
    dma16(gx1, &sX[0][w * 8 + 4][0]);
    dma16(gw0, &sW[0][w * 24][0]);
    dma16(gw1, &sW[0][w * 24 + 8][0]);
    dma16(gw2, &sW[0][w * 24 + 16][0]);
    dma16(gx0 + 64, &sX[1][w * 8][0]);
    dma16(gx1 + 64, &sX[1][w * 8 + 4][0]);
    dma16(gw0 + 64, &sW[1][w * 24][0]);
    dma16(gw1 + 64, &sW[1][w * 24 + 8][0]);
    dma16(gw2 + 64, &sW[1][w * 24 + 16][0]);

    int bi = 0;
    for (int kb = 0; kb < Cd; kb += 64) {
        if (kb != Cd - 64) WAITV(5);     // tile kb resident; tile kb+64 in flight
        else               WAITV(0);     // last tile: drain
        BARRIER();
        if (kb + 128 < Cd) {             // stage tile kb+128 (reuse dist 3: safe)
            const int bn = (bi >= 1) ? bi - 1 : 2;
            const int kn = kb + 128;
            dma16(gx0 + kn, &sX[bn][w * 8][0]);
            dma16(gx1 + kn, &sX[bn][w * 8 + 4][0]);
            dma16(gw0 + kn, &sW[bn][w * 24][0]);
            dma16(gw1 + kn, &sW[bn][w * 24 + 8][0]);
            dma16(gw2 + kn, &sW[bn][w * 24 + 16][0]);
        }

        #pragma unroll
        for (int ks = 0; ks < 2; ++ks) {
            const int ca = (ks * 8 + quad * 2) ^ ml;        // A chunk of 16
            const float4 lo0 = *(const float4*)&sX[bi][wr * 32 + ml][ca << 2];
            const float4 hi0 = *(const float4*)&sX[bi][wr * 32 + ml][(ca ^ 1) << 2];
            const float4 lo1 = *(const float4*)&sX[bi][wr * 32 + 16 + ml][ca << 2];
            const float4 hi1 = *(const float4*)&sX[bi][wr * 32 + 16 + ml][(ca ^ 1) << 2];
            const bf16x8 a0 = cvt_bf16x8(lo0, hi0);
            const bf16x8 a1 = cvt_bf16x8(lo1, hi1);
            const int cb0 = (ks * 4 + quad) ^ (ml & 7);     // B chunk of 8
            const bf16x8 b0 = *(const bf16x8*)&sW[bi][wc * 48 + ml][cb0 << 3];
            const bf16x8 b1 = *(const bf16x8*)&sW[bi][wc * 48 + 16 + ml][cb0 << 3];
            const bf16x8 b2 = *(const bf16x8*)&sW[bi][wc * 48 + 32 + ml][cb0 << 3];
            acc[0][0] = MFMA16(a0, b0, acc[0][0]);
            acc[0][1] = MFMA16(a0, b1, acc[0][1]);
            acc[0][2] = MFMA16(a0, b2, acc[0][2]);
            acc[1][0] = MFMA16(a1, b0, acc[1][0]);
            acc[1][1] = MFMA16(a1, b1, acc[1][1]);
            acc[1][2] = MFMA16(a1, b2, acc[1][2]);
        }
        bi = (bi == 2) ? 0 : bi + 1;
    }

    const int b = (int)(r0 >> 12);
    #pragma unroll
    for (int g = 0; g < 2; ++g) {
        const long rowb = r0 + wr * 32 + g * 16 + quad * 4;
        const int  tloc = (int)(rowb & 4095);
        #pragma unroll
        for (int f = 0; f < 3; ++f) {
            const int base = wc * 48 + f * 16;
            const int sel  = base >> 6;
            const int h    = (base & 63) + ml;
            if (sel == 0) {
                #pragma unroll
                for (int rr = 0; rr < 4; ++rr)
                    qw[(rowb + rr) * H + h] = (bf16)(acc[g][f][rr] * QSCALE);
            } else if (sel == 1) {
                #pragma unroll
                for (int rr = 0; rr < 4; ++rr)
                    kw[(rowb + rr) * H + h] = (bf16)acc[g][f][rr];
            } else {
                bf16x4 pv;
                #pragma unroll
                for (int rr = 0; rr < 4; ++rr) pv[rr] = (bf16)acc[g][f][rr];
                *(bf16x4*)(vtw + ((long)(b * H + h)) * T + tloc) = pv;
            }
        }
    }
}

// ---------------------------------------------------------------------------
// Kernel 3: split-K causal flash chunk v4. Triple-buffered K/V DMA with raw
// s_barrier + vmcnt(4) depth-2 pipeline; ONE barrier per iteration.
// grid (64 qt, 8 chunk, 4 b), 256 thr, 2 blocks/CU (58 KB LDS).
// ---------------------------------------------------------------------------
__global__ __launch_bounds__(256, 2) void attn_kernel(const bf16* __restrict__ qw,
                                                      const bf16* __restrict__ kw,
                                                      const bf16* __restrict__ vtw,
                                                      float* __restrict__ pO,
                                                      float* __restrict__ pL) {
    const int qt = blockIdx.x;
    const int c  = blockIdx.y;
    const int b  = blockIdx.z;
    const int g  = qt >> 3, r = qt & 7;
    if (c > g) return;

    const int tid  = threadIdx.x;
    const int lane = tid & 63;
    const int w    = tid >> 6;
    const int ml   = lane & 15;
    const int quad = lane >> 4;
    const int mx   = ml & 7;

    __shared__ bf16 sK[3][64][64];
    __shared__ bf16 sVt[3][64][64];
    __shared__ bf16 sP[4][16][72];

    const int t0 = qt * 64;

    const bf16* q0 = qw + ((long)b * T + t0 + w * 16 + ml) * H;
    const bf16x8 aq0 = *(const bf16x8*)(q0 + quad * 8);
    const bf16x8 aq1 = *(const bf16x8*)(q0 + 32 + quad * 8);
    WAITV(0);   // retire q loads so they don't entangle with DMA vmcnt counting

    f32x4 O[4];
    #pragma unroll
    for (int ht = 0; ht < 4; ++ht) O[ht] = f32x4{0.f, 0.f, 0.f, 0.f};
    float lrow[4] = {0.f, 0.f, 0.f, 0.f};

    const int trow = t0 + w * 16 + quad * 4;
    const int jt0 = c * CH;
    const int jt1 = (c == g) ? qt + 1 : (c + 1) * CH;

    const int drow = w * 8 + (lane >> 3);
    const int dsw  = ((lane & 7) ^ (drow & 7)) << 3;
    const bf16* kbase = kw + (long)b * T * H;
    const bf16* vbase = vtw + (long)b * H * T;
    const long koffA = (long)drow * H + dsw;
    const long koffB = koffA + 32 * H;
    const long voffA = (long)drow * T + dsw;
    const long voffB = voffA + (long)32 * T;

    // prologue: tiles jt0 (buf0) and jt0+1 (buf1); 4 DMAs per tile per wave
    {
        const long ks0 = (long)jt0 * 64;
        dma16(kbase + ks0 * H + koffA, &sK[0][w * 8][0]);
        dma16(kbase + ks0 * H + koffB, &sK[0][32 + w * 8][0]);
        dma16(vbase + ks0 + voffA, &sVt[0][w * 8][0]);
        dma16(vbase + ks0 + voffB, &sVt[0][32 + w * 8][0]);
        if (jt0 + 1 < jt1) {
            const long ks1 = ks0 + 64;
            dma16(kbase + ks1 * H + koffA, &sK[1][w * 8][0]);
            dma16(kbase + ks1 * H + koffB, &sK[1][32 + w * 8][0]);
            dma16(vbase + ks1 + voffA, &sVt[1][w * 8][0]);
            dma16(vbase + ks1 + voffB, &sVt[1][32 + w * 8][0]);
        }
    }

    int bi = 0;
    for (int jt = jt0; jt < jt1; ++jt) {
        if (jt + 1 < jt1) WAITV(4);      // tile jt resident; jt+1 in flight
        else              WAITV(0);
        BARRIER();
        if (jt + 2 < jt1) {              // stage tile jt+2 (reuse dist 3: safe)
            const int bn = (bi >= 1) ? bi - 1 : 2;
            const long ksn = (long)(jt + 2) * 64;
            dma16(kbase + ksn * H + koffA, &sK[bn][w * 8][0]);
            dma16(kbase + ksn * H + koffB, &sK[bn][32 + w * 8][0]);
            dma16(vbase + ksn + voffA, &sVt[bn][w * 8][0]);
            dma16(vbase + ksn + voffB, &sVt[bn][32 + w * 8][0]);
        }

        const int s0 = jt * 64;
        const bool diag = (jt == qt);
        #pragma unroll
        for (int nt = 0; nt < 4; ++nt) {
            f32x4 sacc = f32x4{0.f, 0.f, 0.f, 0.f};
            sacc = MFMA16(aq0, *(const bf16x8*)&sK[bi][nt * 16 + ml][(quad ^ mx) << 3], sacc);
            sacc = MFMA16(aq1, *(const bf16x8*)&sK[bi][nt * 16 + ml][((4 + quad) ^ mx) << 3], sacc);
            const int col = s0 + nt * 16 + ml;
            #pragma unroll
            for (int rr = 0; rr < 4; ++rr) {
                const float p = (diag && col > trow + rr) ? 0.f : __expf(sacc[rr]);
                lrow[rr] += p;
                sP[w][quad * 4 + rr][nt * 16 + ml] = (bf16)p;
            }
        }
        asm volatile("s_waitcnt lgkmcnt(0)" ::: "memory");  // wave-private sP RAW

        #pragma unroll
        for (int ks = 0; ks < 2; ++ks) {
            const bf16x8 ap = *(const bf16x8*)&sP[w][ml][ks * 32 + quad * 8];
            #pragma unroll
            for (int ht = 0; ht < 4; ++ht)
                O[ht] = MFMA16(ap,
                    *(const bf16x8*)&sVt[bi][ht * 16 + ml][(((ks << 2) + quad) ^ mx) << 3],
                    O[ht]);
        }
        bi = (bi == 2) ? 0 : bi + 1;
    }

    #pragma unroll
    for (int d = 1; d < 16; d <<= 1)
        #pragma unroll
        for (int rr = 0; rr < 4; ++rr)
            lrow[rr] += __shfl_xor(lrow[rr], d, 64);

    const long slot = (long)b * SLOTS_PER_B + (long)(g + 1) * (4 * g + r) + c;
    float* po = pO + slot * 4096 + (w * 16) * 64;
    #pragma unroll
    for (int ht = 0; ht < 4; ++ht)
        #pragma unroll
        for (int rr = 0; rr < 4; ++rr)
            po[(quad * 4 + rr) * 64 + ht * 16 + ml] = O[ht][rr];
    if (ml == 0) {
        #pragma unroll
        for (int rr = 0; rr < 4; ++rr)
            pL[slot * 64 + w * 16 + quad * 4 + rr] = lrow[rr];
    }
}

// ---------------------------------------------------------------------------
// Kernel 4: combine partials v2. grid (64 qt, 4 b, 4 row-slices), 256 thr.
// ---------------------------------------------------------------------------
__global__ __launch_bounds__(256) void combine_kernel(const float* __restrict__ pO,
                                                      const float* __restrict__ pL,
                                                      float* __restrict__ out) {
    const int qt = blockIdx.x;
    const int b  = blockIdx.y;
    const int rq = blockIdx.z;      // 16-row slice
    const int g  = qt >> 3, r = qt & 7;
    const int nch = g + 1;
    const long slot0 = (long)b * SLOTS_PER_B + (long)(g + 1) * (4 * g + r);

    const int tid = threadIdx.x;
    const int row = rq * 16 + (tid >> 4);   // 0..63
    const int c4  = (tid & 15) * 4;

    f32x4 o = f32x4{0.f, 0.f, 0.f, 0.f};
    float l = 0.f;
    for (int cc = 0; cc < nch; ++cc) {
        o += *(const f32x4*)(pO + (slot0 + cc) * 4096 + row * 64 + c4);
        l += pL[(slot0 + cc) * 64 + row];
    }
    const float inv = 1.f / l;
    f32x4 v = o;
    v[0] *= inv; v[1] *= inv; v[2] *= inv; v[3] *= inv;
    *(f32x4*)(out + ((long)b * T + qt * 64 + row) * H + c4) = v;
}

// ---------------------------------------------------------------------------
extern "C" void kernel_launch(void* const* d_in, const int* in_sizes, int n_in,
                              void* d_out, int out_size, void* d_ws, size_t ws_size,
                              hipStream_t stream) {
    const float* x  = (const float*)d_in[0];
    const float* Wq = (const float*)d_in[1];
    const float* Wk = (const float*)d_in[2];
    const float* Wv = (const float*)d_in[3];
    float* out = (float*)d_out;

    char* ws = (char*)d_ws;
    const size_t WT_BYTES = (size_t)NG * Cd * sizeof(bf16);
    const size_t QK_BYTES = (size_t)Bn * T * H * sizeof(bf16);
    const size_t PO_OFF   = WT_BYTES + 3 * QK_BYTES;
    const size_t PO_BYTES = (size_t)Bn * SLOTS_PER_B * 4096 * sizeof(float);
    bf16*  Wt  = (bf16*)ws;
    bf16*  qw  = (bf16*)(ws + WT_BYTES);
    bf16*  kw  = (bf16*)(ws + WT_BYTES + QK_BYTES);
    bf16*  vtw = (bf16*)(ws + WT_BYTES + 2 * QK_BYTES);
    float* pO  = (float*)(ws + PO_OFF);
    float* pL  = (float*)(ws + PO_OFF + PO_BYTES);

    wt_kernel<<<dim3(16, 3), dim3(256), 0, stream>>>(Wq, Wk, Wv, Wt);
    proj_kernel<<<dim3((Bn * T) / 64), dim3(512), 0, stream>>>(x, Wt, qw, kw, vtw);
    attn_kernel<<<dim3(T / 64, CH, Bn), dim3(256), 0, stream>>>(qw, kw, vtw, pO, pL);
    combine_kernel<<<dim3(T / 64, Bn, 4), dim3(256), 0, stream>>>(pO, pL, out);
}

// Round 8
// 158.180 us; speedup vs baseline: 1.0107x; 1.0107x over previous
//
#include <hip/hip_runtime.h>
#include <hip/hip_bf16.h>

typedef __bf16 bf16;
typedef __bf16 bf16x8 __attribute__((ext_vector_type(8)));
typedef __bf16 bf16x4 __attribute__((ext_vector_type(4)));
typedef float  f32x4  __attribute__((ext_vector_type(4)));

#define MFMA16(A, B, C) __builtin_amdgcn_mfma_f32_16x16x32_bf16((A), (B), (C), 0, 0, 0)

static constexpr int Bn = 4;
static constexpr int T  = 4096;
static constexpr int Cd = 1024;
static constexpr int H  = 64;
static constexpr int NG = 192;
static constexpr int CH = 8;            // K-tiles (64 keys) per split-K chunk
static constexpr int SLOTS_PER_B = 144; // sum_{m=0..31} ceil((2m+2)/8)
static constexpr float QSCALE = 0.03125f; // 1/sqrt(C) = 1/32, folded into q

// async global->LDS DMA, 16B per lane; LDS dest = wave-uniform base + lane*16
__device__ inline void dma16(const void* g, void* l) {
    __builtin_amdgcn_global_load_lds(
        (const __attribute__((address_space(1))) unsigned int*)g,
        (__attribute__((address_space(3))) unsigned int*)l, 16, 0, 0);
}

__device__ inline bf16x8 cvt_bf16x8(float4 a, float4 b) {
    bf16x8 r;
    r[0] = (bf16)a.x; r[1] = (bf16)a.y; r[2] = (bf16)a.z; r[3] = (bf16)a.w;
    r[4] = (bf16)b.x; r[5] = (bf16)b.y; r[6] = (bf16)b.z; r[7] = (bf16)b.w;
    return r;
}

// ---------------------------------------------------------------------------
// Kernel 1: coalesced transpose W=[Wq|Wk|Wv] ([C][H] fp32) -> Wt[192][1024] bf16
// ---------------------------------------------------------------------------
__global__ __launch_bounds__(256) void wt_kernel(const float* __restrict__ Wq,
                                                 const float* __restrict__ Wk,
                                                 const float* __restrict__ Wv,
                                                 bf16* __restrict__ Wt) {
    __shared__ float s[64][65];
    const int cb = blockIdx.x;
    const int m  = blockIdx.y;
    const float* W = (m == 0) ? Wq : (m == 1) ? Wk : Wv;
    for (int i = threadIdx.x; i < 64 * 64; i += 256) {
        const int c = i >> 6, h = i & 63;
        s[c][h] = W[(cb * 64 + c) * H + h];
    }
    __syncthreads();
    for (int i = threadIdx.x; i < 64 * 64; i += 256) {
        const int n = i >> 6, c = i & 63;
        Wt[(m * 64 + n) * Cd + cb * 64 + c] = (bf16)s[c][n];
    }
}

// ---------------------------------------------------------------------------
// Kernel 2: QKV projection (R6 v6, best known). grid = M/32 = 512 blocks,
// 512 thr = 8 waves (2x4): wave (wr,wc) computes rows [wr*16,+16) x cols
// [wc*48,+48). x AND Wt staged via DMA into double-buffered swizzled LDS.
// ---------------------------------------------------------------------------
__global__ __launch_bounds__(512, 4) void proj_kernel(const float* __restrict__ x,
                                                      const bf16* __restrict__ Wt,
                                                      bf16* __restrict__ qw,
                                                      bf16* __restrict__ kw,
                                                      bf16* __restrict__ vtw) {
    const int tid  = threadIdx.x;
    const int lane = tid & 63;
    const int w    = tid >> 6;       // 0..7
    const int wr   = w >> 2;         // 0..1 row-group
    const int wc   = w & 3;          // 0..3 col-group
    const int ml   = lane & 15;
    const int quad = lane >> 4;

    const long r0 = (long)blockIdx.x * 32;

    __shared__ float sX[2][32][64];   // 8 KB/buf, 16B chunks swizzled c^(r&15)
    __shared__ bf16  sW[2][192][64];  // 24 KB/buf, 16B chunks swizzled c^(r&7)

    const int xrow = w * 4 + (lane >> 4);
    const float* gx = x + (r0 + xrow) * Cd + (((lane & 15) ^ (xrow & 15)) << 2);
    const int wchunk = ((lane & 7) ^ (lane >> 3)) << 3;
    const bf16* gw0 = Wt + (long)(w * 24 + 0 + (lane >> 3)) * Cd + wchunk;
    const bf16* gw1 = Wt + (long)(w * 24 + 8 + (lane >> 3)) * Cd + wchunk;
    const bf16* gw2 = Wt + (long)(w * 24 + 16 + (lane >> 3)) * Cd + wchunk;

    f32x4 acc[3];
    #pragma unroll
    for (int j = 0; j < 3; ++j) acc[j] = f32x4{0.f, 0.f, 0.f, 0.f};

    dma16(gx, &sX[0][w * 4][0]);
    dma16(gw0, &sW[0][w * 24 + 0][0]);
    dma16(gw1, &sW[0][w * 24 + 8][0]);
    dma16(gw2, &sW[0][w * 24 + 16][0]);
    __syncthreads();

    const int arow = wr * 16 + ml;
    const int brow0 = wc * 48 + ml;
    const int bsw = ml & 7;

    int buf = 0;
    for (int kb = 0; kb < Cd; kb += 64) {
        if (kb + 64 < Cd) {
            dma16(gx + kb + 64, &sX[buf ^ 1][w * 4][0]);
            dma16(gw0 + kb + 64, &sW[buf ^ 1][w * 24 + 0][0]);
            dma16(gw1 + kb + 64, &sW[buf ^ 1][w * 24 + 8][0]);
            dma16(gw2 + kb + 64, &sW[buf ^ 1][w * 24 + 16][0]);
        }

        #pragma unroll
        for (int ks = 0; ks < 2; ++ks) {
            const int ca = (ks * 8 + quad * 2) ^ ml;
            const float4 lo = *(const float4*)&sX[buf][arow][ca << 2];
            const float4 hi = *(const float4*)&sX[buf][arow][(ca ^ 1) << 2];
            const bf16x8 af = cvt_bf16x8(lo, hi);
            const int cb0 = (ks * 4 + quad) ^ bsw;
            acc[0] = MFMA16(af, *(const bf16x8*)&sW[buf][brow0 + 0][cb0 << 3], acc[0]);
            acc[1] = MFMA16(af, *(const bf16x8*)&sW[buf][brow0 + 16][cb0 << 3], acc[1]);
            acc[2] = MFMA16(af, *(const bf16x8*)&sW[buf][brow0 + 32][cb0 << 3], acc[2]);
        }

        __syncthreads();
        buf ^= 1;
    }

    const int b = (int)(r0 >> 12);
    const long rowb = r0 + wr * 16 + quad * 4;
    const int  tloc = (int)(rowb & 4095);

    #pragma unroll
    for (int f = 0; f < 3; ++f) {
        const int base = wc * 48 + f * 16;
        const int sel  = base >> 6;
        const int h    = (base & 63) + ml;
        if (sel == 0) {
            #pragma unroll
            for (int rr = 0; rr < 4; ++rr)
                qw[(rowb + rr) * H + h] = (bf16)(acc[f][rr] * QSCALE);
        } else if (sel == 1) {
            #pragma unroll
            for (int rr = 0; rr < 4; ++rr)
                kw[(rowb + rr) * H + h] = (bf16)acc[f][rr];
        } else {
            bf16x4 pv;
            #pragma unroll
            for (int rr = 0; rr < 4; ++rr) pv[rr] = (bf16)acc[f][rr];
            *(bf16x4*)(vtw + ((long)(b * H + h)) * T + tloc) = pv;
        }
    }
}

// ---------------------------------------------------------------------------
// Kernel 3: split-K causal flash, BM=128. grid (32 m, 8 chunk, 4 b), 256 thr.
// Wave w owns Q rows [w*32, w*32+32) (two 16-row MFMA groups). K/V staged via
// DMA dbuf (R6 structure); each staged tile now feeds 2x the Q rows.
// nch(m) = ceil((2m+2)/8) = (m>>2)+1. 50 KB LDS -> 3 blocks/CU.
// ---------------------------------------------------------------------------
__global__ __launch_bounds__(256, 3) void attn_kernel(const bf16* __restrict__ qw,
                                                      const bf16* __restrict__ kw,
                                                      const bf16* __restrict__ vtw,
                                                      float* __restrict__ pO,
                                                      float* __restrict__ pL) {
    const int m = blockIdx.x;       // Q-block of 128 rows
    const int c = blockIdx.y;       // chunk
    const int b = blockIdx.z;
    const int k = (m >> 2) + 1;     // number of chunks for this m
    if (c >= k) return;             // uniform early exit

    const int tid  = threadIdx.x;
    const int lane = tid & 63;
    const int w    = tid >> 6;
    const int ml   = lane & 15;
    const int quad = lane >> 4;
    const int mx   = ml & 7;

    __shared__ bf16 sK[2][64][64];
    __shared__ bf16 sVt[2][64][64];
    __shared__ bf16 sP[4][32][72];

    const int t0  = m * 128;
    const int wq0 = t0 + w * 32;    // wave's first Q row

    const bf16* qb = qw + ((long)b * T + wq0 + ml) * H;
    const bf16x8 aq[2][2] = {
        { *(const bf16x8*)(qb + quad * 8),          *(const bf16x8*)(qb + 32 + quad * 8) },
        { *(const bf16x8*)(qb + 16 * H + quad * 8), *(const bf16x8*)(qb + 16 * H + 32 + quad * 8) },
    };

    f32x4 O[2][4];
    float lrow[2][4];
    #pragma unroll
    for (int g = 0; g < 2; ++g)
        #pragma unroll
        for (int j = 0; j < 4; ++j) { O[g][j] = f32x4{0.f, 0.f, 0.f, 0.f}; lrow[g][j] = 0.f; }

    const int jt0 = c * CH;
    const int jte = 2 * m + 2;
    const int jt1 = ((c + 1) * CH < jte) ? (c + 1) * CH : jte;

    const int drow = w * 8 + (lane >> 3);
    const int dsw  = ((lane & 7) ^ (drow & 7)) << 3;
    const bf16* kbase = kw + (long)b * T * H;
    const bf16* vbase = vtw + (long)b * H * T;
    const long koffA = (long)drow * H + dsw;
    const long koffB = koffA + 32 * H;
    const long voffA = (long)drow * T + dsw;
    const long voffB = voffA + (long)32 * T;

    {
        const long ks0 = (long)jt0 * 64;
        dma16(kbase + ks0 * H + koffA, &sK[0][w * 8][0]);
        dma16(kbase + ks0 * H + koffB, &sK[0][32 + w * 8][0]);
        dma16(vbase + ks0 + voffA, &sVt[0][w * 8][0]);
        dma16(vbase + ks0 + voffB, &sVt[0][32 + w * 8][0]);
    }
    __syncthreads();

    int buf = 0;
    for (int jt = jt0; jt < jt1; ++jt) {
        if (jt + 1 < jt1) {
            const long ksn = (long)(jt + 1) * 64;
            dma16(kbase + ksn * H + koffA, &sK[buf ^ 1][w * 8][0]);
            dma16(kbase + ksn * H + koffB, &sK[buf ^ 1][32 + w * 8][0]);
            dma16(vbase + ksn + voffA, &sVt[buf ^ 1][w * 8][0]);
            dma16(vbase + ksn + voffB, &sVt[buf ^ 1][32 + w * 8][0]);
        }

        const int s0 = jt * 64;
        if (s0 <= wq0 + 31) {                 // else: tile fully masked for wave
            const bool diag = (s0 + 63 > wq0);
            #pragma unroll
            for (int g = 0; g < 2; ++g) {
                const int rowb = wq0 + g * 16 + quad * 4;
                #pragma unroll
                for (int nt = 0; nt < 4; ++nt) {
                    f32x4 sacc = f32x4{0.f, 0.f, 0.f, 0.f};
                    sacc = MFMA16(aq[g][0], *(const bf16x8*)&sK[buf][nt * 16 + ml][(quad ^ mx) << 3], sacc);
                    sacc = MFMA16(aq[g][1], *(const bf16x8*)&sK[buf][nt * 16 + ml][((4 + quad) ^ mx) << 3], sacc);
                    const int col = s0 + nt * 16 + ml;
                    #pragma unroll
                    for (int rr = 0; rr < 4; ++rr) {
                        const float p = (diag && col > rowb + rr) ? 0.f : __expf(sacc[rr]);
                        lrow[g][rr] += p;
                        sP[w][g * 16 + quad * 4 + rr][nt * 16 + ml] = (bf16)p;
                    }
                }
            }
            asm volatile("s_waitcnt lgkmcnt(0)" ::: "memory");  // wave-private sP RAW

            #pragma unroll
            for (int g = 0; g < 2; ++g)
                #pragma unroll
                for (int ks = 0; ks < 2; ++ks) {
                    const bf16x8 ap = *(const bf16x8*)&sP[w][g * 16 + ml][ks * 32 + quad * 8];
                    #pragma unroll
                    for (int ht = 0; ht < 4; ++ht)
                        O[g][ht] = MFMA16(ap,
                            *(const bf16x8*)&sVt[buf][ht * 16 + ml][(((ks << 2) + quad) ^ mx) << 3],
                            O[g][ht]);
                }
        }

        __syncthreads();
        buf ^= 1;
    }

    #pragma unroll
    for (int d = 1; d < 16; d <<= 1)
        #pragma unroll
        for (int g = 0; g < 2; ++g)
            #pragma unroll
            for (int rr = 0; rr < 4; ++rr)
                lrow[g][rr] += __shfl_xor(lrow[g][rr], d, 64);

    const long slot = (long)b * SLOTS_PER_B + 2 * k * (k - 1) + (m & 3) * k + c;
    float* po = pO + slot * 8192;
    #pragma unroll
    for (int g = 0; g < 2; ++g) {
        #pragma unroll
        for (int ht = 0; ht < 4; ++ht)
            #pragma unroll
            for (int rr = 0; rr < 4; ++rr)
                po[(w * 32 + g * 16 + quad * 4 + rr) * 64 + ht * 16 + ml] = O[g][ht][rr];
        if (ml == 0) {
            #pragma unroll
            for (int rr = 0; rr < 4; ++rr)
                pL[slot * 128 + w * 32 + g * 16 + quad * 4 + rr] = lrow[g][rr];
        }
    }
}

// ---------------------------------------------------------------------------
// Kernel 4: combine partials. grid (32 m, 4 b, 8 row-slices), 256 thr.
// ---------------------------------------------------------------------------
__global__ __launch_bounds__(256) void combine_kernel(const float* __restrict__ pO,
                                                      const float* __restrict__ pL,
                                                      float* __restrict__ out) {
    const int m  = blockIdx.x;
    const int b  = blockIdx.y;
    const int rq = blockIdx.z;      // 16-row slice of 128
    const int k  = (m >> 2) + 1;
    const long slot0 = (long)b * SLOTS_PER_B + 2 * k * (k - 1) + (m & 3) * k;

    const int tid = threadIdx.x;
    const int row = rq * 16 + (tid >> 4);   // 0..127
    const int c4  = (tid & 15) * 4;

    f32x4 o = f32x4{0.f, 0.f, 0.f, 0.f};
    float l = 0.f;
    for (int cc = 0; cc < k; ++cc) {
        o += *(const f32x4*)(pO + (slot0 + cc) * 8192 + row * 64 + c4);
        l += pL[(slot0 + cc) * 128 + row];
    }
    const float inv = 1.f / l;
    f32x4 v = o;
    v[0] *= inv; v[1] *= inv; v[2] *= inv; v[3] *= inv;
    *(f32x4*)(out + ((long)b * T + m * 128 + row) * H + c4) = v;
}

// ---------------------------------------------------------------------------
extern "C" void kernel_launch(void* const* d_in, const int* in_sizes, int n_in,
                              void* d_out, int out_size, void* d_ws, size_t ws_size,
                              hipStream_t stream) {
    const float* x  = (const float*)d_in[0];
    const float* Wq = (const float*)d_in[1];
    const float* Wk = (const float*)d_in[2];
    const float* Wv = (const float*)d_in[3];
    float* out = (float*)d_out;

    char* ws = (char*)d_ws;
    const size_t WT_BYTES = (size_t)NG * Cd * sizeof(bf16);
    const size_t QK_BYTES = (size_t)Bn * T * H * sizeof(bf16);
    const size_t PO_OFF   = WT_BYTES + 3 * QK_BYTES;
    const size_t PO_BYTES = (size_t)Bn * SLOTS_PER_B * 8192 * sizeof(float); // 18.9 MiB
    bf16*  Wt  = (bf16*)ws;
    bf16*  qw  = (bf16*)(ws + WT_BYTES);
    bf16*  kw  = (bf16*)(ws + WT_BYTES + QK_BYTES);
    bf16*  vtw = (bf16*)(ws + WT_BYTES + 2 * QK_BYTES);
    float* pO  = (float*)(ws + PO_OFF);
    float* pL  = (float*)(ws + PO_OFF + PO_BYTES);

    wt_kernel<<<dim3(16, 3), dim3(256), 0, stream>>>(Wq, Wk, Wv, Wt);
    proj_kernel<<<dim3((Bn * T) / 32), dim3(512), 0, stream>>>(x, Wt, qw, kw, vtw);
    attn_kernel<<<dim3(T / 128, CH, Bn), dim3(256), 0, stream>>>(qw, kw, vtw, pO, pL);
    combine_kernel<<<dim3(T / 128, Bn, 8), dim3(256), 0, stream>>>(pO, pL, out);
}